// Round 1
// baseline (1841.612 us; speedup 1.0000x reference)
//
#include <hip/hip_runtime.h>
#include <hip/hip_fp16.h>
#include <math.h>

// Problem constants (reference file)
#define NPTS   500000
#define CIN    16
#define COUT   64
#define PE     32
#define GRID_H 256
#define GRID_W 256
#define NCELL  (GRID_H * GRID_W)   // 65536

#define PT_BLOCKS  1024
#define PT_THREADS 256

// Per-thread LDS slot: 33 dwords (132 B). Stride 33 -> bank = (33*t + k) % 32
// = (t + k) % 32 -> exactly 2 lanes/bank per access = conflict-free (free on CDNA4).
//   phase 1: dwords [0,16) hold the 16 fp32 input features (GEMM1)
//   phase 2: bytes  [0,128) hold 64 fp16 GELU outputs      (GEMM2)

__device__ __forceinline__ int cell_index(float v) {
    float nf = fminf(fmaxf((v + 1.0f) * 0.5f, 0.0f), 1.0f);
    int i = (int)floorf(nf * 256.0f);
    return i > 255 ? 255 : i;
}

__global__ __launch_bounds__(PT_THREADS, 4)
void point_kernel(const float* __restrict__ pos,
                  const float* __restrict__ feats,
                  const float* __restrict__ W1,
                  const float* __restrict__ b1,
                  const float* __restrict__ ln_g,
                  const float* __restrict__ ln_b,
                  const float* __restrict__ W2,
                  const float* __restrict__ b2,
                  const int*   __restrict__ ax1p,
                  const int*   __restrict__ ax2p,
                  float* __restrict__ sums,   // [COUT][NCELL] == d_out
                  float* __restrict__ cnt)    // [NCELL]
{
    __shared__ float lds[PT_THREADS * 33];
    float* slot = &lds[threadIdx.x * 33];

    const int a1 = ax1p[0];
    const int a2 = ax2p[0];
    const int stride = gridDim.x * blockDim.x;

    for (int p = blockIdx.x * blockDim.x + threadIdx.x; p < NPTS; p += stride) {
        // ---- load point inputs --------------------------------------------
        const float px = pos[p * 3 + 0];
        const float py = pos[p * 3 + 1];
        const float pz = pos[p * 3 + 2];

        const float* fp = feats + (size_t)p * CIN;
        #pragma unroll 1
        for (int k = 0; k < CIN; ++k) slot[k] = fp[k];

        // ---- GEMM1: h = combined @ W1 + b1 --------------------------------
        float h[COUT];
        #pragma unroll
        for (int c = 0; c < COUT; ++c) h[c] = b1[c];

        // features part (k = 0..15)
        #pragma unroll 1
        for (int k = 0; k < CIN; ++k) {
            float v = slot[k];
            const float* Wr = W1 + k * COUT;   // uniform address -> s_load
            #pragma unroll
            for (int c = 0; c < COUT; ++c) h[c] += Wr[c] * v;
        }

        // positional-encoding part: for dim d, rows 16+d*64+k (sin), +32 (cos)
        // angle(d,k) = pos_d/2 * pi * 2^(k/32); running product by 2^(1/32)
        #pragma unroll 1
        for (int d = 0; d < 3; ++d) {
            float pv  = (d == 0) ? px : ((d == 1) ? py : pz);
            float ang = pv * 1.57079632679489662f;   // pos/2 * pi
            const float* Wp = W1 + (CIN + d * 2 * PE) * COUT;
            #pragma unroll 1
            for (int k = 0; k < PE; ++k) {
                float s  = __sinf(ang);
                float co = __cosf(ang);
                const float* Ws = Wp + k * COUT;
                const float* Wc = Wp + (PE + k) * COUT;
                #pragma unroll
                for (int c = 0; c < COUT; ++c) h[c] += Ws[c] * s;
                #pragma unroll
                for (int c = 0; c < COUT; ++c) h[c] += Wc[c] * co;
                ang *= 1.02189714865411668f;         // 2^(1/32)
            }
        }

        // ---- LayerNorm + GELU (tanh approx, |err| <= ~1e-3) ---------------
        float s1 = 0.0f, s2 = 0.0f;
        #pragma unroll
        for (int c = 0; c < COUT; ++c) { s1 += h[c]; s2 += h[c] * h[c]; }
        float mu   = s1 * (1.0f / COUT);
        float var  = s2 * (1.0f / COUT) - mu * mu;
        float rstd = rsqrtf(var + 1e-5f);

        __half* gh = (__half*)slot;   // 64 fp16 values, bytes [0,128) of slot
        #pragma unroll
        for (int c = 0; c < COUT; ++c) {
            float x  = (h[c] - mu) * rstd * ln_g[c] + ln_b[c];
            float x2 = x * x;
            float u  = x * (0.7978845608028654f + 0.0356774081363001f * x2);
            float e  = __expf(2.0f * u);
            float t  = 1.0f - 2.0f / (e + 1.0f);   // tanh(u), branchless
            float g  = 0.5f * x * (1.0f + t);
            gh[c] = __float2half(g);
        }

        // ---- GEMM2: feat = g @ W2 + b2 ------------------------------------
        float facc[COUT];
        #pragma unroll
        for (int c = 0; c < COUT; ++c) facc[c] = b2[c];

        #pragma unroll 1
        for (int j = 0; j < COUT; ++j) {
            float gj = __half2float(gh[j]);
            const float* Wr = W2 + j * COUT;   // uniform -> s_load
            #pragma unroll
            for (int c = 0; c < COUT; ++c) facc[c] += Wr[c] * gj;
        }

        // ---- scatter-add into [c][cell] grid ------------------------------
        float pa1 = (a1 == 0) ? px : ((a1 == 1) ? py : pz);
        float pa2 = (a2 == 0) ? px : ((a2 == 1) ? py : pz);
        int flat = cell_index(pa1) * GRID_W + cell_index(pa2);

        #pragma unroll
        for (int c = 0; c < COUT; ++c)
            unsafeAtomicAdd(&sums[c * NCELL + flat], facc[c]);
        unsafeAtomicAdd(&cnt[flat], 1.0f);
    }
}

__global__ void finalize_kernel(float* __restrict__ out,
                                const float* __restrict__ cnt)
{
    int t = blockIdx.x * blockDim.x + threadIdx.x;   // grid sized exactly
    float c = cnt[t & (NCELL - 1)];
    out[t] = out[t] / fmaxf(c, 1.0f);
}

extern "C" void kernel_launch(void* const* d_in, const int* in_sizes, int n_in,
                              void* d_out, int out_size, void* d_ws, size_t ws_size,
                              hipStream_t stream) {
    (void)in_sizes; (void)n_in; (void)out_size; (void)ws_size;
    const float* pos   = (const float*)d_in[0];
    const float* feats = (const float*)d_in[1];
    const float* W1    = (const float*)d_in[2];
    const float* b1    = (const float*)d_in[3];
    const float* ln_g  = (const float*)d_in[4];
    const float* ln_b  = (const float*)d_in[5];
    const float* W2    = (const float*)d_in[6];
    const float* b2    = (const float*)d_in[7];
    const int*   ax1   = (const int*)d_in[8];
    const int*   ax2   = (const int*)d_in[9];

    float* out = (float*)d_out;          // accumulates sums in [COUT][NCELL]
    float* cnt = (float*)d_ws;           // [NCELL] counts (needs 256 KB of ws)

    hipMemsetAsync(d_out, 0, (size_t)COUT * NCELL * sizeof(float), stream);
    hipMemsetAsync(d_ws, 0, (size_t)NCELL * sizeof(float), stream);

    point_kernel<<<PT_BLOCKS, PT_THREADS, 0, stream>>>(
        pos, feats, W1, b1, ln_g, ln_b, W2, b2, ax1, ax2, out, cnt);

    finalize_kernel<<<(COUT * NCELL) / 256, 256, 0, stream>>>(out, cnt);
}

// Round 2
// 1735.604 us; speedup vs baseline: 1.0611x; 1.0611x over previous
//
#include <hip/hip_runtime.h>
#include <math.h>

// Problem constants (reference file)
#define NPTS   500000
#define CIN    16
#define COUT   64
#define PE     32
#define GRID_H 256
#define GRID_W 256
#define NCELL  (GRID_H * GRID_W)   // 65536

#define PT_THREADS 256
#define PT_BLOCKS  ((NPTS + PT_THREADS - 1) / PT_THREADS)   // 1954

typedef float    v16f  __attribute__((ext_vector_type(16)));
typedef _Float16 h2v   __attribute__((ext_vector_type(2)));

__device__ __forceinline__ int cell_index(float v) {
    float nf = fminf(fmaxf((v + 1.0f) * 0.5f, 0.0f), 1.0f);
    int i = (int)floorf(nf * 256.0f);
    return i > 255 ? 255 : i;
}

// Accumulate one weight row (64 floats, wave-uniform address -> s_load) scaled
// by a per-lane scalar into the four 16-wide accumulators.
#define ACC_ROW(W, row, val)                                    \
    {                                                           \
        v16f wa = (W)[4 * (row) + 0];                           \
        v16f wb = (W)[4 * (row) + 1];                           \
        v16f wc = (W)[4 * (row) + 2];                           \
        v16f wd = (W)[4 * (row) + 3];                           \
        h0 += wa * (val); h1 += wb * (val);                     \
        h2 += wc * (val); h3 += wd * (val);                     \
    }

__global__ __launch_bounds__(PT_THREADS, 3)
void point_kernel(const float* __restrict__ pos,
                  const float* __restrict__ feats,
                  const float* __restrict__ W1,
                  const float* __restrict__ b1,
                  const float* __restrict__ ln_g,
                  const float* __restrict__ ln_b,
                  const float* __restrict__ W2,
                  const float* __restrict__ b2,
                  const int*   __restrict__ ax1p,
                  const int*   __restrict__ ax2p,
                  float* __restrict__ sums,   // [COUT][NCELL] == d_out
                  float* __restrict__ cnt)    // [NCELL]
{
    const int gid   = blockIdx.x * PT_THREADS + threadIdx.x;
    const bool valid = (gid < NPTS);
    const int p      = valid ? gid : (NPTS - 1);   // clamp: body stays uniform

    // ---- per-point inputs (vector loads, per-lane) ------------------------
    const float px = pos[p * 3 + 0];
    const float py = pos[p * 3 + 1];
    const float pz = pos[p * 3 + 2];

    const float4* fvp = (const float4*)(feats + (size_t)p * CIN);
    const float4 f0 = fvp[0], f1 = fvp[1], f2 = fvp[2], f3 = fvp[3];

    // ---- GEMM1: h = [feats | PE(pos)] @ W1 + b1 ---------------------------
    const v16f* W1v = (const v16f*)W1;
    const v16f* B1v = (const v16f*)b1;
    v16f h0 = B1v[0], h1 = B1v[1], h2 = B1v[2], h3 = B1v[3];

    // feature rows 0..15, fully unrolled (static float4 element extraction)
    ACC_ROW(W1v,  0, f0.x) ACC_ROW(W1v,  1, f0.y) ACC_ROW(W1v,  2, f0.z) ACC_ROW(W1v,  3, f0.w)
    ACC_ROW(W1v,  4, f1.x) ACC_ROW(W1v,  5, f1.y) ACC_ROW(W1v,  6, f1.z) ACC_ROW(W1v,  7, f1.w)
    ACC_ROW(W1v,  8, f2.x) ACC_ROW(W1v,  9, f2.y) ACC_ROW(W1v, 10, f2.z) ACC_ROW(W1v, 11, f2.w)
    ACC_ROW(W1v, 12, f3.x) ACC_ROW(W1v, 13, f3.y) ACC_ROW(W1v, 14, f3.z) ACC_ROW(W1v, 15, f3.w)

    // positional encoding rows: dim d -> rows 16+d*64+k (sin), +32 (cos)
    // angle(d,k) = pos_d * (pi/2) * 2^(k/32); running product by 2^(1/32)
    #pragma unroll 1
    for (int d = 0; d < 3; ++d) {
        float pv  = (d == 0) ? px : ((d == 1) ? py : pz);
        float ang = pv * 1.57079632679489662f;
        int  base = CIN + d * 2 * PE;
        #pragma unroll 1
        for (int k = 0; k < PE; ++k) {
            float s  = __sinf(ang);
            float co = __cosf(ang);
            ACC_ROW(W1v, base + k,       s)
            ACC_ROW(W1v, base + PE + k,  co)
            ang *= 1.02189714865411668f;          // 2^(1/32)
        }
    }

    // ---- LayerNorm --------------------------------------------------------
    v16f ts = h0 + h1 + h2 + h3;
    v16f tq = h0 * h0 + h1 * h1 + h2 * h2 + h3 * h3;
    float s1 = 0.0f, s2 = 0.0f;
    #pragma unroll
    for (int i = 0; i < 16; ++i) { s1 += ts[i]; s2 += tq[i]; }
    float mu   = s1 * (1.0f / COUT);
    float var  = s2 * (1.0f / COUT) - mu * mu;
    float rstd = __builtin_amdgcn_rsqf(var + 1e-5f);

    // ---- GELU (tanh approx) -> packed fp16 in 32 VGPRs --------------------
    const v16f* LG = (const v16f*)ln_g;
    const v16f* LB = (const v16f*)ln_b;
    h2v gh[32];
    #pragma unroll
    for (int t4 = 0; t4 < 4; ++t4) {
        v16f hv = (t4 == 0) ? h0 : ((t4 == 1) ? h1 : ((t4 == 2) ? h2 : h3));
        v16f lg = LG[t4], lb = LB[t4];
        #pragma unroll
        for (int i = 0; i < 16; i += 2) {
            float xa = (hv[i]     - mu) * rstd * lg[i]     + lb[i];
            float xb = (hv[i + 1] - mu) * rstd * lg[i + 1] + lb[i + 1];
            float ua = xa * (0.7978845608028654f + 0.0356774081363001f * xa * xa);
            float ub = xb * (0.7978845608028654f + 0.0356774081363001f * xb * xb);
            float ea = __expf(2.0f * ua);
            float eb = __expf(2.0f * ub);
            float ta = 1.0f - 2.0f * __builtin_amdgcn_rcpf(ea + 1.0f);
            float tb = 1.0f - 2.0f * __builtin_amdgcn_rcpf(eb + 1.0f);
            h2v g2;
            g2[0] = (_Float16)(0.5f * xa * (1.0f + ta));
            g2[1] = (_Float16)(0.5f * xb * (1.0f + tb));
            gh[t4 * 8 + (i >> 1)] = g2;
        }
    }

    // ---- GEMM2: feat = g @ W2 + b2  (fully unrolled, g in registers) ------
    const v16f* W2v = (const v16f*)W2;
    const v16f* B2v = (const v16f*)b2;
    {
        v16f a0 = B2v[0], a1 = B2v[1], a2 = B2v[2], a3 = B2v[3];
        #pragma unroll
        for (int j = 0; j < COUT; ++j) {
            float gj = (float)gh[j >> 1][j & 1];   // static after unroll
            v16f wa = W2v[4 * j + 0];
            v16f wb = W2v[4 * j + 1];
            v16f wc = W2v[4 * j + 2];
            v16f wd = W2v[4 * j + 3];
            a0 += wa * gj; a1 += wb * gj; a2 += wc * gj; a3 += wd * gj;
        }

        // ---- scatter-add into [c][cell] grid (only divergent region) ------
        const int ax1 = ax1p[0], ax2 = ax2p[0];
        float pa1 = (ax1 == 0) ? px : ((ax1 == 1) ? py : pz);
        float pa2 = (ax2 == 0) ? px : ((ax2 == 1) ? py : pz);
        int flat = cell_index(pa1) * GRID_W + cell_index(pa2);

        if (valid) {
            #pragma unroll
            for (int i = 0; i < 16; ++i)
                unsafeAtomicAdd(&sums[(i)      * NCELL + flat], a0[i]);
            #pragma unroll
            for (int i = 0; i < 16; ++i)
                unsafeAtomicAdd(&sums[(i + 16) * NCELL + flat], a1[i]);
            #pragma unroll
            for (int i = 0; i < 16; ++i)
                unsafeAtomicAdd(&sums[(i + 32) * NCELL + flat], a2[i]);
            #pragma unroll
            for (int i = 0; i < 16; ++i)
                unsafeAtomicAdd(&sums[(i + 48) * NCELL + flat], a3[i]);
            unsafeAtomicAdd(&cnt[flat], 1.0f);
        }
    }
}

__global__ void finalize_kernel(float* __restrict__ out,
                                const float* __restrict__ cnt)
{
    int t = blockIdx.x * blockDim.x + threadIdx.x;   // grid sized exactly
    float c = cnt[t & (NCELL - 1)];
    out[t] = out[t] / fmaxf(c, 1.0f);
}

extern "C" void kernel_launch(void* const* d_in, const int* in_sizes, int n_in,
                              void* d_out, int out_size, void* d_ws, size_t ws_size,
                              hipStream_t stream) {
    (void)in_sizes; (void)n_in; (void)out_size; (void)ws_size;
    const float* pos   = (const float*)d_in[0];
    const float* feats = (const float*)d_in[1];
    const float* W1    = (const float*)d_in[2];
    const float* b1    = (const float*)d_in[3];
    const float* ln_g  = (const float*)d_in[4];
    const float* ln_b  = (const float*)d_in[5];
    const float* W2    = (const float*)d_in[6];
    const float* b2    = (const float*)d_in[7];
    const int*   ax1   = (const int*)d_in[8];
    const int*   ax2   = (const int*)d_in[9];

    float* out = (float*)d_out;          // accumulates sums in [COUT][NCELL]
    float* cnt = (float*)d_ws;           // [NCELL] counts (256 KB of ws)

    hipMemsetAsync(d_out, 0, (size_t)COUT * NCELL * sizeof(float), stream);
    hipMemsetAsync(d_ws, 0, (size_t)NCELL * sizeof(float), stream);

    point_kernel<<<PT_BLOCKS, PT_THREADS, 0, stream>>>(
        pos, feats, W1, b1, ln_g, ln_b, W2, b2, ax1, ax2, out, cnt);

    finalize_kernel<<<(COUT * NCELL) / 256, 256, 0, stream>>>(out, cnt);
}